// Round 10
// baseline (26.256 us; speedup 1.0000x reference)
//
#include <hip/hip_runtime.h>
#include <stdint.h>

#define BB 16
#define CI 64
#define CO 64
#define HH 32
#define WW 32

// full adder / half adder on 32-lane bitsets
__device__ __forceinline__ void fadd(uint32_t a, uint32_t b, uint32_t c,
                                     uint32_t& s, uint32_t& cy) {
    uint32_t t = a ^ b;
    s = t ^ c;
    cy = (t & c) | (a & b);
}
__device__ __forceinline__ void hadd(uint32_t a, uint32_t b, uint32_t& s, uint32_t& cy) {
    s = a ^ b;
    cy = a & b;
}
__device__ __forceinline__ void add5(const uint32_t* a, const uint32_t* b, uint32_t* r) {
    uint32_t c;
    hadd(a[0], b[0], r[0], c);
#pragma unroll
    for (int k = 1; k < 5; ++k) fadd(a[k], b[k], c, r[k], c);
    r[5] = c;
}
__device__ __forceinline__ void add6(const uint32_t* a, const uint32_t* b, uint32_t* r) {
    uint32_t c;
    hadd(a[0], b[0], r[0], c);
#pragma unroll
    for (int k = 1; k < 6; ++k) fadd(a[k], b[k], c, r[k], c);
    r[6] = c;
}

// ---- dispatch 1: pack inverted 9-bit weight signs only (16 blocks)
__global__ __launch_bounds__(256) void packw_kernel(const float* __restrict__ w,
                                                    uint32_t* __restrict__ winv) {
    int idx = blockIdx.x * 256 + threadIdx.x;   // 0..4095
    int ci = idx & 63, co = idx >> 6;           // coalesced over ci
    uint32_t bits = 0;
#pragma unroll
    for (int t = 0; t < 9; ++t)
        bits |= (w[(co * 9 + t) * CI + ci] > 0.f ? 1u : 0u) << t;
    winv[ci * CO + co] = bits ^ 0x1FFu;         // [ci][co], inverted: match = xn ^ winv
}

// ---- dispatch 2: blocks 0..511 = (b,y) SWAR interior; 512..639 = y-border rows.
// x is self-packed from floats via ballot (read exactly once, coalesced).
__global__ __launch_bounds__(256) void core_kernel(const float* __restrict__ x,
                                                   const uint32_t* __restrict__ winv,
                                                   float* __restrict__ out) {
    __shared__ uint32_t wlds[CI * CO];       // 16 KiB
    __shared__ uint4 xr4[CI];                // rows y-1,y,y+1 per ci
    __shared__ uint32_t xnb[2][CI];          // 9-bit border windows (px=0 / px=31)
    __shared__ uint32_t red[4][CO][5];       // per-ciq 5 bit-planes
    __shared__ uint32_t planes7[CO][7];      // reduced 7 bit-planes
    __shared__ int bord[CO][2][2];           // x-border partial sums

    const int bid = blockIdx.x;
    const int tid = threadIdx.x;

    if (bid < BB * HH) {
        const int b = bid >> 5, y = bid & 31;
        if (y == 0 || y == HH - 1) return;   // uniform exit before any barrier

        {   // stage winv (coalesced packed read, 16 KiB)
            const uint4* src = (const uint4*)winv;
            uint4* dst = (uint4*)wlds;
#pragma unroll
            for (int i = 0; i < 4; ++i) dst[tid + i * 256] = src[tid + i * 256];
        }
        // ballot-pack 3 x-rows from floats: 192 tasks, 2 half-wave tasks/iter/wave
        {
            const int wave = tid >> 6, lane = tid & 63;
            const int half = lane >> 5, px = lane & 31;
#pragma unroll
            for (int j = 0; j < 24; ++j) {
                int task = wave * 48 + j * 2 + half;
                int r = task >> 6, ci = task & 63;
                float v = x[((b * CI + ci) * HH + (y - 1 + r)) * WW + px];  // y interior
                unsigned long long mask = __ballot(v > 0.f);
                if (px == 0)
                    ((uint32_t*)&xr4[ci])[r] = (uint32_t)(half ? (mask >> 32) : mask);
            }
        }
        __syncthreads();
        // precompute 9-bit x-border windows from packed rows
        if (tid < 128) {
            int side = tid >> 6, ci = tid & 63;
            uint4 xr = xr4[ci];
            uint32_t n0, n1, n2;
            if (side == 0) {                 // px=0: dx=-1 taps zeroed
                n0 = (xr.x & 3u) << 1; n1 = (xr.y & 3u) << 1; n2 = (xr.z & 3u) << 1;
            } else {                         // px=31: dx=+1 taps zeroed
                n0 = (xr.x >> 30) & 3u; n1 = (xr.y >> 30) & 3u; n2 = (xr.z >> 30) & 3u;
            }
            xnb[side][ci] = n0 | (n1 << 3) | (n2 << 6);
        }
        __syncthreads();

        const int co = tid & 63, ciq = tid >> 6;

        // ---- SWAR majority-of-9 over 32 pixels, 16 ci per thread ----
        uint32_t maj[16];
#pragma unroll
        for (int i = 0; i < 16; ++i) {
            const int ci = ciq * 16 + i;
            const uint4 xr = xr4[ci];
            const uint32_t wn = wlds[ci * CO + co];
            const uint32_t T0 = xr.x << 1, T1 = xr.x, T2 = xr.x >> 1;
            const uint32_t T3 = xr.y << 1, T4 = xr.y, T5 = xr.y >> 1;
            const uint32_t T6 = xr.z << 1, T7 = xr.z, T8 = xr.z >> 1;
            const uint32_t m0 = T0 ^ (uint32_t)(-(int)((wn >> 0) & 1));
            const uint32_t m1 = T1 ^ (uint32_t)(-(int)((wn >> 1) & 1));
            const uint32_t m2 = T2 ^ (uint32_t)(-(int)((wn >> 2) & 1));
            const uint32_t m3 = T3 ^ (uint32_t)(-(int)((wn >> 3) & 1));
            const uint32_t m4 = T4 ^ (uint32_t)(-(int)((wn >> 4) & 1));
            const uint32_t m5 = T5 ^ (uint32_t)(-(int)((wn >> 5) & 1));
            const uint32_t m6 = T6 ^ (uint32_t)(-(int)((wn >> 6) & 1));
            const uint32_t m7 = T7 ^ (uint32_t)(-(int)((wn >> 7) & 1));
            const uint32_t m8 = T8 ^ (uint32_t)(-(int)((wn >> 8) & 1));
            uint32_t s1, c1, s2, c2, s3, c3, S, C, D, E;
            fadd(m0, m1, m2, s1, c1);
            fadd(m3, m4, m5, s2, c2);
            fadd(m6, m7, m8, s3, c3);
            fadd(s1, s2, s3, S, C);              // m = S + 2C + 2D + 4E
            fadd(c1, c2, c3, D, E);
            maj[i] = (E & (S | C | D)) | (~E & (S & C & D));   // m >= 5
        }

        // ---- CSA: 16 maj bits -> 5 planes ----
        uint32_t A[5], Bw[5];
        fadd(maj[0], maj[1], maj[2], A[0], Bw[0]);
        fadd(maj[3], maj[4], maj[5], A[1], Bw[1]);
        fadd(maj[6], maj[7], maj[8], A[2], Bw[2]);
        fadd(maj[9], maj[10], maj[11], A[3], Bw[3]);
        fadd(maj[12], maj[13], maj[14], A[4], Bw[4]);
        uint32_t u1, v1, u2, v2, p0, v3;
        fadd(A[0], A[1], A[2], u1, v1);
        fadd(A[3], A[4], maj[15], u2, v2);
        hadd(u1, u2, p0, v3);
        uint32_t e1, f1, e2, f2, e3, f3, p1, f4;
        fadd(Bw[0], Bw[1], Bw[2], e1, f1);
        fadd(Bw[3], Bw[4], v1, e2, f2);
        fadd(e1, e2, v2, e3, f3);
        hadd(e3, v3, p1, f4);
        uint32_t g1, h1, p2, h2, p3, p4;
        fadd(f1, f2, f3, g1, h1);
        hadd(g1, f4, p2, h2);
        hadd(h1, h2, p3, p4);
        red[ciq][co][0] = p0; red[ciq][co][1] = p1; red[ciq][co][2] = p2;
        red[ciq][co][3] = p3; red[ciq][co][4] = p4;

        // ---- x-border fixup from precomputed windows: N=6, lut const ----
        {
            const int fco = tid & 63, side = (tid >> 6) & 1, cih = tid >> 7;
            const uint32_t vmask = side ? 0x0DBu : 0x1B6u;
            const uint32_t lut = 0xAAA40u;       // (m>3)+(m>2) at 2-bit slot 2m
            int acc = 0;
#pragma unroll 4
            for (int i = 0; i < 32; ++i) {
                const int ci = cih * 32 + i;
                const uint32_t xn = xnb[side][ci];
                const uint32_t wn = wlds[ci * CO + fco];
                const uint32_t mm = (uint32_t)__popc((xn ^ wn) & vmask);
                acc += (lut >> (2 * mm)) & 3u;
            }
            bord[fco][side][cih] = acc;
        }
        __syncthreads();

        // ---- reduce 4 ciq counts -> 7 planes (wave 0) ----
        if (tid < 64) {
            uint32_t x0[6], x1[6], rr[7];
            add5(red[0][tid], red[1][tid], x0);
            add5(red[2][tid], red[3][tid], x1);
            add6(x0, x1, rr);
#pragma unroll
            for (int k = 0; k < 7; ++k) planes7[tid][k] = rr[k];
        }
        __syncthreads();

        // ---- extract + store ----
        {
            const int oco = tid & 63, q = tid >> 6;
            uint32_t pl[7];
#pragma unroll
            for (int k = 0; k < 7; ++k) pl[k] = planes7[oco][k];
            float vals[8];
#pragma unroll
            for (int j = 0; j < 8; ++j) {
                const int px = q * 8 + j;
                uint32_t cnt = 0;
#pragma unroll
                for (int k = 0; k < 7; ++k) cnt += ((pl[k] >> px) & 1u) << k;
                vals[j] = (float)(2 * (int)cnt - CI);
            }
            if (q == 0) vals[0] = (float)(bord[oco][0][0] + bord[oco][0][1] - CI);
            if (q == 3) vals[7] = (float)(bord[oco][1][0] + bord[oco][1][1] - CI);
            float4* op = (float4*)&out[((size_t)(b * CO + oco) * HH + y) * WW + q * 8];
            op[0] = make_float4(vals[0], vals[1], vals[2], vals[3]);
            op[1] = make_float4(vals[4], vals[5], vals[6], vals[7]);
        }
    } else {
        // ---- y-border rows (y=0,31): generic-LUT, block = (b, yb, co-quarter) ----
        const int idx = bid - BB * HH;            // 0..127
        const int b = idx >> 3, yb = (idx >> 2) & 1, coq = idx & 3;
        const int y = yb * (HH - 1);
        for (int i = tid; i < CI * 16; i += 256) {  // winv subset [ci][16 co]
            int ci = i >> 4, c = i & 15;
            wlds[i] = winv[ci * CO + coq * 16 + c];
        }
        // ballot-pack 3 x-rows (OOB row -> 0)
        {
            const int wave = tid >> 6, lane = tid & 63;
            const int half = lane >> 5, px = lane & 31;
#pragma unroll
            for (int j = 0; j < 24; ++j) {
                int task = wave * 48 + j * 2 + half;
                int r = task >> 6, ci = task & 63;
                int yy = y - 1 + r;
                float v = (yy >= 0 && yy < HH) ? x[((b * CI + ci) * HH + yy) * WW + px] : 0.f;
                unsigned long long mask = __ballot(v > 0.f);
                if (px == 0)
                    ((uint32_t*)&xr4[ci])[r] = (uint32_t)(half ? (mask >> 32) : mask);
            }
        }
        __syncthreads();

        const int px = tid & 31, cog = tid >> 5;   // 2 co each
        const uint32_t rowm = (px > 0 ? 1u : 0u) | 2u | (px < WW - 1 ? 4u : 0u);
        const uint32_t vmask = (y > 0 ? rowm : 0u) | (rowm << 3) |
                               (y < HH - 1 ? (rowm << 6) : 0u);
        const uint32_t N = __popc(vmask);
        const uint32_t nt1 = N >> 1, nt2 = (N - 1) >> 1;
        uint32_t lut = 0;
        for (uint32_t m = 1; m <= 9; ++m)
            lut |= (uint32_t)((m > nt1) + (m > nt2)) << (2 * m);
        int a0 = 0, a1 = 0;
        for (int ci = 0; ci < CI; ++ci) {
            const uint4 xr = xr4[ci];
            const uint32_t n0 = (uint32_t)((((uint64_t)xr.x) << 1) >> px) & 7u;
            const uint32_t n1 = (uint32_t)((((uint64_t)xr.y) << 1) >> px) & 7u;
            const uint32_t n2 = (uint32_t)((((uint64_t)xr.z) << 1) >> px) & 7u;
            const uint32_t xn = n0 | (n1 << 3) | (n2 << 6);
            const uint32_t w0 = wlds[ci * 16 + cog * 2 + 0];
            const uint32_t w1 = wlds[ci * 16 + cog * 2 + 1];
            uint32_t mm;
            mm = (uint32_t)__popc((xn ^ w0) & vmask); a0 += (lut >> (2 * mm)) & 3u;
            mm = (uint32_t)__popc((xn ^ w1) & vmask); a1 += (lut >> (2 * mm)) & 3u;
        }
        const int co0 = coq * 16 + cog * 2;
        out[((size_t)(b * CO + co0 + 0) * HH + y) * WW + px] = (float)(a0 - CI);
        out[((size_t)(b * CO + co0 + 1) * HH + y) * WW + px] = (float)(a1 - CI);
    }
}

extern "C" void kernel_launch(void* const* d_in, const int* in_sizes, int n_in,
                              void* d_out, int out_size, void* d_ws, size_t ws_size,
                              hipStream_t stream) {
    const float* x = (const float*)d_in[0];
    const float* w = (const float*)d_in[1];
    float* out = (float*)d_out;

    uint32_t* winv = (uint32_t*)d_ws;           // 4096 words

    packw_kernel<<<16, 256, 0, stream>>>(w, winv);
    core_kernel<<<BB * HH + 128, 256, 0, stream>>>(x, winv, out);
}

// Round 11
// 20.708 us; speedup vs baseline: 1.2679x; 1.2679x over previous
//
#include <hip/hip_runtime.h>
#include <stdint.h>

#define BB 16
#define CI 64
#define CO 64
#define HH 32
#define WW 32

// full adder / half adder on 32-lane bitsets
__device__ __forceinline__ void fadd(uint32_t a, uint32_t b, uint32_t c,
                                     uint32_t& s, uint32_t& cy) {
    uint32_t t = a ^ b;
    s = t ^ c;
    cy = (t & c) | (a & b);
}
__device__ __forceinline__ void hadd(uint32_t a, uint32_t b, uint32_t& s, uint32_t& cy) {
    s = a ^ b;
    cy = a & b;
}
__device__ __forceinline__ void add4p(const uint32_t* a, const uint32_t* b, uint32_t* r) {
    uint32_t c;
    hadd(a[0], b[0], r[0], c);
#pragma unroll
    for (int k = 1; k < 4; ++k) fadd(a[k], b[k], c, r[k], c);
    r[4] = c;
}
__device__ __forceinline__ void add5p(const uint32_t* a, const uint32_t* b, uint32_t* r) {
    uint32_t c;
    hadd(a[0], b[0], r[0], c);
#pragma unroll
    for (int k = 1; k < 5; ++k) fadd(a[k], b[k], c, r[k], c);
    r[5] = c;
}
__device__ __forceinline__ void add6p(const uint32_t* a, const uint32_t* b, uint32_t* r) {
    uint32_t c;
    hadd(a[0], b[0], r[0], c);
#pragma unroll
    for (int k = 1; k < 6; ++k) fadd(a[k], b[k], c, r[k], c);
    r[6] = c;
}
// majority (>=5 of 9) over 32-lane bitsets
__device__ __forceinline__ uint32_t maj9(uint32_t m0, uint32_t m1, uint32_t m2,
                                         uint32_t m3, uint32_t m4, uint32_t m5,
                                         uint32_t m6, uint32_t m7, uint32_t m8) {
    uint32_t s1, c1, s2, c2, s3, c3, S, C, D, E;
    fadd(m0, m1, m2, s1, c1);
    fadd(m3, m4, m5, s2, c2);
    fadd(m6, m7, m8, s3, c3);
    fadd(s1, s2, s3, S, C);          // m = S + 2C + 2D + 4E
    fadd(c1, c2, c3, D, E);
    return (E & (S | C | D)) | (~E & (S & C & D));
}
// 8 majority bits -> 4 planes (count 0..8)
__device__ __forceinline__ void csa8(const uint32_t* m, uint32_t* p) {
    uint32_t s1, c1, s2, c2, s3, c3, c4, s5, c5, c6;
    fadd(m[0], m[1], m[2], s1, c1);
    fadd(m[3], m[4], m[5], s2, c2);
    hadd(m[6], m[7], s3, c3);
    fadd(s1, s2, s3, p[0], c4);
    fadd(c1, c2, c3, s5, c5);
    hadd(s5, c4, p[1], c6);
    hadd(c5, c6, p[2], p[3]);
}

// ---- dispatch 1 (verified R9): pack x row-bitmasks + inverted weight signs
__global__ __launch_bounds__(256) void pack_kernel(const float* __restrict__ x,
                                                   const float* __restrict__ w,
                                                   uint32_t* __restrict__ xbits,
                                                   uint32_t* __restrict__ winv) {
    const int bid = blockIdx.x;
    const int tid = threadIdx.x;
    if (bid < 512) {
        const int base = bid * 2048;
#pragma unroll
        for (int it = 0; it < 8; ++it) {
            int p = base + it * 256 + tid;
            unsigned long long mask = __ballot(x[p] > 0.0f);
            int lane = tid & 63;
            if ((lane & 31) == 0)
                xbits[p >> 5] = (lane & 32) ? (uint32_t)(mask >> 32) : (uint32_t)mask;
        }
    } else {
        int idx = (bid - 512) * 256 + tid;         // 0..4095
        int ci = idx & 63, co = idx >> 6;          // coalesced over ci
        uint32_t bits = 0;
#pragma unroll
        for (int t = 0; t < 9; ++t)
            bits |= (w[(co * 9 + t) * CI + ci] > 0.f ? 1u : 0u) << t;
        winv[ci * CO + co] = bits ^ 0x1FFu;        // [ci][co], inverted
    }
}

// ---- dispatch 2: blocks 0..479 = (b, row-pair, co-half) SWAR interior;
//                  blocks 480..607 = y-border rows (R9-verified path).
__global__ __launch_bounds__(256) void core_kernel(const uint32_t* __restrict__ xbits,
                                                   const uint32_t* __restrict__ winv,
                                                   float* __restrict__ out) {
    __shared__ uint32_t wlds[CI * 32];       // interior: [ci][co_l] 8 KiB; border uses 4 KiB
    __shared__ uint4 xr4[CI];                // rows y0-1 .. y0+2 per ci
    __shared__ uint32_t xnb[2][2][CI];       // [row][side] 9-bit border windows
    __shared__ uint32_t red[2][8][32][4];    // [row][ciq8][co_l][plane]
    __shared__ uint32_t planes7[2][32][7];   // [row][co_l][plane]
    __shared__ int bord[2][32][2][4];        // [row][co_l][side][ci-quarter]

    const int bid = blockIdx.x;
    const int tid = threadIdx.x;

    if (bid < 480) {
        const int b = bid / 30;
        const int rem = bid - b * 30;
        const int pi = rem >> 1, ch = rem & 1;
        const int y0 = 2 * pi + 1;               // rows y0, y0+1 (1..30)

        {   // stage winv half: [ci][ch*32 .. +32], 512 uint4
            const uint4* src = (const uint4*)winv;
            uint4* dst = (uint4*)wlds;
#pragma unroll
            for (int u = 0; u < 2; ++u) {
                int k = tid + u * 256;
                int ci = k >> 3, q = k & 7;
                dst[ci * 8 + q] = src[ci * 16 + ch * 8 + q];
            }
        }
        {   // stage 4 x-rows: 256 tasks
            int r = tid >> 6, ci = tid & 63;
            ((uint32_t*)&xr4[ci])[r] = xbits[(b * CI + ci) * HH + (y0 - 1 + r)];
        }
        __syncthreads();

        // border windows for both rows (256 tasks)
        {
            int row = tid >> 7, side = (tid >> 6) & 1, ci = tid & 63;
            uint4 xr = xr4[ci];
            uint32_t r0 = row ? xr.y : xr.x;
            uint32_t r1 = row ? xr.z : xr.y;
            uint32_t r2 = row ? xr.w : xr.z;
            uint32_t n0, n1, n2;
            if (side == 0) {                 // px=0: dx=-1 taps zeroed
                n0 = (r0 & 3u) << 1; n1 = (r1 & 3u) << 1; n2 = (r2 & 3u) << 1;
            } else {                         // px=31: dx=+1 taps zeroed
                n0 = (r0 >> 30) & 3u; n1 = (r1 >> 30) & 3u; n2 = (r2 >> 30) & 3u;
            }
            xnb[row][side][ci] = n0 | (n1 << 3) | (n2 << 6);
        }

        const int co_l = tid & 31, ciq = tid >> 5;   // 8 groups x 8 ci

        // ---- SWAR maj-of-9, 2 rows per thread, 8 ci ----
        uint32_t maj0[8], maj1[8];
#pragma unroll
        for (int i = 0; i < 8; ++i) {
            const int ci = ciq * 8 + i;
            const uint4 xr = xr4[ci];
            const uint32_t wn = wlds[ci * 32 + co_l];
            uint32_t S0 = (uint32_t)(-(int)((wn >> 0) & 1));
            uint32_t S1 = (uint32_t)(-(int)((wn >> 1) & 1));
            uint32_t S2 = (uint32_t)(-(int)((wn >> 2) & 1));
            uint32_t S3 = (uint32_t)(-(int)((wn >> 3) & 1));
            uint32_t S4 = (uint32_t)(-(int)((wn >> 4) & 1));
            uint32_t S5 = (uint32_t)(-(int)((wn >> 5) & 1));
            uint32_t S6 = (uint32_t)(-(int)((wn >> 6) & 1));
            uint32_t S7 = (uint32_t)(-(int)((wn >> 7) & 1));
            uint32_t S8 = (uint32_t)(-(int)((wn >> 8) & 1));
            const uint32_t l0 = xr.x << 1, h0 = xr.x >> 1;
            const uint32_t l1 = xr.y << 1, h1 = xr.y >> 1;
            const uint32_t l2 = xr.z << 1, h2 = xr.z >> 1;
            const uint32_t l3 = xr.w << 1, h3 = xr.w >> 1;
            maj0[i] = maj9(l0 ^ S0, xr.x ^ S1, h0 ^ S2,
                           l1 ^ S3, xr.y ^ S4, h1 ^ S5,
                           l2 ^ S6, xr.z ^ S7, h2 ^ S8);
            maj1[i] = maj9(l1 ^ S0, xr.y ^ S1, h1 ^ S2,
                           l2 ^ S3, xr.z ^ S4, h2 ^ S5,
                           l3 ^ S6, xr.w ^ S7, h3 ^ S8);
        }
        uint32_t p[4];
        csa8(maj0, p);
        *(uint4*)&red[0][ciq][co_l][0] = make_uint4(p[0], p[1], p[2], p[3]);
        csa8(maj1, p);
        *(uint4*)&red[1][ciq][co_l][0] = make_uint4(p[0], p[1], p[2], p[3]);
        __syncthreads();

        // ---- x-border fixup: (co_l, side, ci-quarter), both rows, wn reused ----
        {
            const int fco = tid & 31, side = (tid >> 5) & 1, cq = (tid >> 6) & 3;
            const uint32_t vmask = side ? 0x0DBu : 0x1B6u;   // N=6
            const uint32_t lut = 0xAAA40u;                   // (m>3)+(m>2) at slot 2m
            int a0 = 0, a1 = 0;
#pragma unroll 4
            for (int i = 0; i < 16; ++i) {
                const int ci = cq * 16 + i;
                const uint32_t wn = wlds[ci * 32 + fco];
                uint32_t mm0 = (uint32_t)__popc((xnb[0][side][ci] ^ wn) & vmask);
                uint32_t mm1 = (uint32_t)__popc((xnb[1][side][ci] ^ wn) & vmask);
                a0 += (lut >> (2 * mm0)) & 3u;
                a1 += (lut >> (2 * mm1)) & 3u;
            }
            bord[0][fco][side][cq] = a0;
            bord[1][fco][side][cq] = a1;
        }
        // ---- reduce 8 ciq counts -> 7 planes (64 threads: row x co_l) ----
        if (tid < 64) {
            const int row = tid >> 5, col = tid & 31;
            uint32_t g[8][4];
#pragma unroll
            for (int k = 0; k < 8; ++k)
                *(uint4*)&g[k][0] = *(const uint4*)&red[row][k][col][0];
            uint32_t t01[5], t23[5], t45[5], t67[5], u0[6], u1[6], rr[7];
            add4p(g[0], g[1], t01);
            add4p(g[2], g[3], t23);
            add4p(g[4], g[5], t45);
            add4p(g[6], g[7], t67);
            add5p(t01, t23, u0);
            add5p(t45, t67, u1);
            add6p(u0, u1, rr);
#pragma unroll
            for (int k = 0; k < 7; ++k) planes7[row][col][k] = rr[k];
        }
        __syncthreads();

        // ---- extract + store: (row, co_l, q) ----
        {
            const int row = tid >> 7, r2 = tid & 127;
            const int col = r2 >> 2, q = r2 & 3;
            uint32_t pl[7];
#pragma unroll
            for (int k = 0; k < 7; ++k) pl[k] = planes7[row][col][k];
            float vals[8];
#pragma unroll
            for (int j = 0; j < 8; ++j) {
                const int px = q * 8 + j;
                uint32_t cnt = 0;
#pragma unroll
                for (int k = 0; k < 7; ++k) cnt += ((pl[k] >> px) & 1u) << k;
                vals[j] = (float)(2 * (int)cnt - CI);
            }
            if (q == 0)
                vals[0] = (float)(bord[row][col][0][0] + bord[row][col][0][1] +
                                  bord[row][col][0][2] + bord[row][col][0][3] - CI);
            if (q == 3)
                vals[7] = (float)(bord[row][col][1][0] + bord[row][col][1][1] +
                                  bord[row][col][1][2] + bord[row][col][1][3] - CI);
            const int co = ch * 32 + col, y = y0 + row;
            float4* op = (float4*)&out[((size_t)(b * CO + co) * HH + y) * WW + q * 8];
            op[0] = make_float4(vals[0], vals[1], vals[2], vals[3]);
            op[1] = make_float4(vals[4], vals[5], vals[6], vals[7]);
        }
    } else {
        // ---- y-border rows (y=0,31): R9-verified generic-LUT path ----
        const int idx = bid - 480;                // 0..127
        const int b = idx >> 3, yb = (idx >> 2) & 1, coq = idx & 3;
        const int y = yb * (HH - 1);
        for (int i = tid; i < CI * 16; i += 256) {  // winv subset [ci][16 co]
            int ci = i >> 4, c = i & 15;
            wlds[i] = winv[ci * CO + coq * 16 + c];
        }
        if (tid < 3 * CI) {
            int r = tid >> 6, ci = tid & 63;
            int yy = y - 1 + r;
            ((uint32_t*)&xr4[ci])[r] = (yy >= 0 && yy < HH) ? xbits[(b * CI + ci) * HH + yy] : 0u;
        }
        __syncthreads();

        const int px = tid & 31, cog = tid >> 5;   // 2 co each
        const uint32_t rowm = (px > 0 ? 1u : 0u) | 2u | (px < WW - 1 ? 4u : 0u);
        const uint32_t vmask = (y > 0 ? rowm : 0u) | (rowm << 3) |
                               (y < HH - 1 ? (rowm << 6) : 0u);
        const uint32_t N = __popc(vmask);
        const uint32_t nt1 = N >> 1, nt2 = (N - 1) >> 1;
        uint32_t lut = 0;
        for (uint32_t m = 1; m <= 9; ++m)
            lut |= (uint32_t)((m > nt1) + (m > nt2)) << (2 * m);
        int a0 = 0, a1 = 0;
        for (int ci = 0; ci < CI; ++ci) {
            const uint4 xr = xr4[ci];
            const uint32_t n0 = (uint32_t)((((uint64_t)xr.x) << 1) >> px) & 7u;
            const uint32_t n1 = (uint32_t)((((uint64_t)xr.y) << 1) >> px) & 7u;
            const uint32_t n2 = (uint32_t)((((uint64_t)xr.z) << 1) >> px) & 7u;
            const uint32_t xn = n0 | (n1 << 3) | (n2 << 6);
            const uint32_t w0 = wlds[ci * 16 + cog * 2 + 0];
            const uint32_t w1 = wlds[ci * 16 + cog * 2 + 1];
            uint32_t mm;
            mm = (uint32_t)__popc((xn ^ w0) & vmask); a0 += (lut >> (2 * mm)) & 3u;
            mm = (uint32_t)__popc((xn ^ w1) & vmask); a1 += (lut >> (2 * mm)) & 3u;
        }
        const int co0 = coq * 16 + cog * 2;
        out[((size_t)(b * CO + co0 + 0) * HH + y) * WW + px] = (float)(a0 - CI);
        out[((size_t)(b * CO + co0 + 1) * HH + y) * WW + px] = (float)(a1 - CI);
    }
}

extern "C" void kernel_launch(void* const* d_in, const int* in_sizes, int n_in,
                              void* d_out, int out_size, void* d_ws, size_t ws_size,
                              hipStream_t stream) {
    const float* x = (const float*)d_in[0];
    const float* w = (const float*)d_in[1];
    float* out = (float*)d_out;

    uint32_t* xbits = (uint32_t*)d_ws;          // 16384 words
    uint32_t* winv = xbits + BB * CI * HH;      // 4096 words

    pack_kernel<<<512 + 16, 256, 0, stream>>>(x, w, xbits, winv);
    core_kernel<<<480 + 128, 256, 0, stream>>>(xbits, winv, out);
}